// Round 21
// baseline (187.159 us; speedup 1.0000x reference)
//
#include <hip/hip_runtime.h>
#include <math.h>

#define BATCH 16
#define SEQ   1024
#define HID   441
#define NH    9
#define KP    448                 // padded hidden (K and N dim of GEMMs)
#define PB    544                 // sum of padded head dims
#define PBE   (SEQ * PB)          // padded elems per batch
#define WTS   (KP * KP)           // one transposed weight matrix

typedef __attribute__((ext_vector_type(8))) short bf16x8;
typedef __attribute__((ext_vector_type(4))) float f32x4;

__constant__ int c_bounds[NH + 1] = {0, 7, 21, 49, 105, 161, 217, 273, 357, 441};
__constant__ int c_dpad[NH] = {32, 32, 32, 64, 64, 64, 64, 96, 96};
__constant__ int c_cum[NH]  = {0, 32, 64, 96, 160, 224, 288, 352, 448};

__device__ __forceinline__ ushort f2bf(float x) {
    union { float f; unsigned u; } v; v.f = x;
    unsigned r = v.u + 0x7FFF + ((v.u >> 16) & 1);   // RNE
    return (ushort)(r >> 16);
}

__device__ __forceinline__ void gld_lds16(const ushort* g, ushort* l) {
    __builtin_amdgcn_global_load_lds(
        (const __attribute__((address_space(1))) unsigned int*)g,
        (__attribute__((address_space(3))) unsigned int*)l, 16, 0, 0);
}

// raw hardware exp2: single v_exp_f32 (args always <= 0 here)
__device__ __forceinline__ float fexp2(float x) {
    return __builtin_amdgcn_exp2f(x);
}

// DPP 16-lane reduction steps (pure VALU — no ds_bpermute):
template<int CTRL>
__device__ __forceinline__ float dpp_max(float x) {
    int m = __builtin_amdgcn_update_dpp(0, __builtin_bit_cast(int, x), CTRL, 0xF, 0xF, true);
    return fmaxf(x, __builtin_bit_cast(float, m));
}
template<int CTRL>
__device__ __forceinline__ float dpp_add(float x) {
    int m = __builtin_amdgcn_update_dpp(0, __builtin_bit_cast(int, x), CTRL, 0xF, 0xF, true);
    return x + __builtin_bit_cast(float, m);
}

// ---------------------------------------------------------------------------
// hs fp32 [16384][441] -> bf16 [16384][448] (pad cols zeroed)
// ---------------------------------------------------------------------------
__global__ __launch_bounds__(256)
void convert_hs(const float* __restrict__ hs, ushort* __restrict__ out)
{
    int t = blockIdx.x * 256 + threadIdx.x;   // 16384*56 threads
    int r = t / 56, cc = t % 56;
    const float* src = hs + (size_t)r * HID + cc * 8;
    union { ushort u[8]; bf16x8 v; } pk;
#pragma unroll
    for (int j = 0; j < 8; ++j) {
        int c = cc * 8 + j;
        pk.u[j] = (c < HID) ? f2bf(src[j]) : (ushort)0;
    }
    *(bf16x8*)(out + (size_t)r * KP + cc * 8) = pk.v;
}

// ---------------------------------------------------------------------------
// W fp32 [441][441] -> W^T bf16 [448][448] (pads zero). blockIdx.y = matrix.
// ---------------------------------------------------------------------------
__global__ __launch_bounds__(256)
void convert_w(const float* __restrict__ W0, const float* __restrict__ W1,
               const float* __restrict__ W2, const float* __restrict__ W3,
               ushort* __restrict__ wt)
{
    const float* W = (blockIdx.y == 0) ? W0 : (blockIdx.y == 1) ? W1
                   : (blockIdx.y == 2) ? W2 : W3;
    ushort* out = wt + (size_t)blockIdx.y * WTS;
    int t = blockIdx.x * 256 + threadIdx.x;   // 448*56 threads
    int n = t / 56, kc = t % 56;
    union { ushort u[8]; bf16x8 v; } pk;
#pragma unroll
    for (int j = 0; j < 8; ++j) {
        int k = kc * 8 + j;
        pk.u[j] = (k < HID && n < HID) ? f2bf(W[(size_t)k * HID + n]) : (ushort)0;
    }
    *(bf16x8*)(out + (size_t)n * KP + kc * 8) = pk.v;
}

// ---------------------------------------------------------------------------
// FULLY-FUSED QKV bf16 MFMA GEMM, 128x64 tile, BK=32, 4 waves (2x2).
// A-tile staged once per K-step; af[] reused across z; 3 accumulator sets.
// z=0: Q -> padded [b][h][s][dp], PRE-SCALED by log2e/sqrt(d)
// z=1: K -> padded [b][h][s][dp]
// z=2: V -> transposed [b][h][dv][s]
// ---------------------------------------------------------------------------
__global__ __launch_bounds__(256)
void gemm_qkv(const ushort* __restrict__ A, const ushort* __restrict__ wt,
              const float* __restrict__ bq, const float* __restrict__ bk,
              const float* __restrict__ bv, ushort* __restrict__ qp,
              ushort* __restrict__ kp, ushort* __restrict__ vp)
{
    __shared__ ushort As[2][128 * 32];       // 16 KB
    __shared__ ushort Bs[2][3][64 * 32];     // 24 KB

    int tid = threadIdx.x;
    int wid = tid >> 6, lane = tid & 63;
    int wm = wid >> 1, wn = wid & 1;
    int lr = lane & 15, lg = lane >> 4;
    int m0 = blockIdx.x * 128, n0 = blockIdx.y * 64;

    const ushort* a_src = A + (size_t)(m0 + (tid >> 2)) * KP + (tid & 3) * 8;
    const ushort* b_src = wt + (size_t)(n0 + (tid >> 2)) * KP + (tid & 3) * 8;

    f32x4 acc[3][4][2];
#pragma unroll
    for (int z = 0; z < 3; ++z)
#pragma unroll
        for (int i = 0; i < 4; ++i)
#pragma unroll
            for (int j = 0; j < 2; ++j) acc[z][i][j] = (f32x4){0.f, 0.f, 0.f, 0.f};

    auto stage = [&](int buf, int k0) {
        gld_lds16(a_src + k0,                     &As[buf][tid * 8]);
        gld_lds16(a_src + 64 * KP + k0,           &As[buf][2048 + tid * 8]);
        gld_lds16(b_src + k0,                     &Bs[buf][0][tid * 8]);
        gld_lds16(b_src + (size_t)WTS + k0,       &Bs[buf][1][tid * 8]);
        gld_lds16(b_src + 2 * (size_t)WTS + k0,   &Bs[buf][2][tid * 8]);
    };

    stage(0, 0);
#pragma unroll 2
    for (int t = 0; t < 14; ++t) {
        int buf = t & 1;
        __syncthreads();                       // buf staged, prev reads done
        if (t < 13) stage(buf ^ 1, (t + 1) * 32);

        bf16x8 af[4];
#pragma unroll
        for (int mr = 0; mr < 4; ++mr)
            af[mr] = *(const bf16x8*)&As[buf][(wm * 64 + mr * 16 + lr) * 32 + lg * 8];

#pragma unroll
        for (int z = 0; z < 3; ++z) {
            bf16x8 bf[2];
#pragma unroll
            for (int nt = 0; nt < 2; ++nt)
                bf[nt] = *(const bf16x8*)&Bs[buf][z][(wn * 32 + nt * 16 + lr) * 32 + lg * 8];
#pragma unroll
            for (int mr = 0; mr < 4; ++mr)
#pragma unroll
                for (int nt = 0; nt < 2; ++nt)
                    acc[z][mr][nt] = __builtin_amdgcn_mfma_f32_16x16x32_bf16(af[mr], bf[nt], acc[z][mr][nt], 0, 0, 0);
        }
    }

    // ---- epilogue (verbatim per-z paths) ----
    int bb = m0 >> 10;
    int srow = (m0 & 1023) + wm * 64;

#pragma unroll
    for (int z = 0; z < 3; ++z) {
        const float* bias = (z == 0) ? bq : (z == 1) ? bk : bv;
#pragma unroll
        for (int nt = 0; nt < 2; ++nt) {
            int gn = n0 + wn * 32 + nt * 16 + lr;
            bool ok = gn < HID;
            int gcl = ok ? gn : 0;
            float bval = ok ? bias[gcl] : 0.f;
            int hh = 0;
            while (gcl >= c_bounds[hh + 1]) ++hh;
            int off = gcl - c_bounds[hh];
            int dph = c_dpad[hh];
            size_t hbase = (size_t)bb * PBE + ((size_t)c_cum[hh] << 10);
            float cs = (z == 0)
                     ? rsqrtf((float)(c_bounds[hh + 1] - c_bounds[hh])) * 1.44269504f
                     : 1.0f;

#pragma unroll
            for (int mr = 0; mr < 4; ++mr)
#pragma unroll
                for (int r = 0; r < 4; ++r) {
                    if (!ok) continue;
                    int s = srow + mr * 16 + lg * 4 + r;
                    float val = (acc[z][mr][nt][r] + bval) * cs;
                    if (z == 0) {
                        qp[hbase + (size_t)s * dph + off] = f2bf(val);
                    } else if (z == 1) {
                        kp[hbase + (size_t)s * dph + off] = f2bf(val);
                    } else {
                        vp[hbase + ((size_t)off << 10) + s] = f2bf(val);
                    }
                }
        }
    }
}

// ---------------------------------------------------------------------------
// O-projection bf16 MFMA GEMM, 128x64 tile: out[16384][441] fp32 = ctx@Wo^T+bo
// ---------------------------------------------------------------------------
__global__ __launch_bounds__(256)
void gemm_out(const ushort* __restrict__ A, const ushort* __restrict__ Bt,
              const float* __restrict__ bias, float* __restrict__ Cout)
{
    __shared__ ushort As[2][128 * 32];
    __shared__ ushort Bs[2][64 * 32];

    int tid = threadIdx.x;
    int wid = tid >> 6, lane = tid & 63;
    int wm = wid >> 1, wn = wid & 1;
    int lr = lane & 15, lg = lane >> 4;
    int m0 = blockIdx.x * 128, n0 = blockIdx.y * 64;

    const ushort* a_src = A + (size_t)(m0 + (tid >> 2)) * KP + (tid & 3) * 8;
    const ushort* b_src = Bt + (size_t)(n0 + (tid >> 2)) * KP + (tid & 3) * 8;

    f32x4 acc[4][2];
#pragma unroll
    for (int i = 0; i < 4; ++i)
#pragma unroll
        for (int j = 0; j < 2; ++j) acc[i][j] = (f32x4){0.f, 0.f, 0.f, 0.f};

    auto stage = [&](int buf, int k0) {
        gld_lds16(a_src + k0,            &As[buf][tid * 8]);
        gld_lds16(a_src + 64 * KP + k0,  &As[buf][2048 + tid * 8]);
        gld_lds16(b_src + k0,            &Bs[buf][tid * 8]);
    };

    stage(0, 0);
#pragma unroll 2
    for (int t = 0; t < 14; ++t) {
        int buf = t & 1;
        __syncthreads();
        if (t < 13) stage(buf ^ 1, (t + 1) * 32);

        bf16x8 af[4], bf[2];
#pragma unroll
        for (int mr = 0; mr < 4; ++mr)
            af[mr] = *(const bf16x8*)&As[buf][(wm * 64 + mr * 16 + lr) * 32 + lg * 8];
#pragma unroll
        for (int nt = 0; nt < 2; ++nt)
            bf[nt] = *(const bf16x8*)&Bs[buf][(wn * 32 + nt * 16 + lr) * 32 + lg * 8];
#pragma unroll
        for (int mr = 0; mr < 4; ++mr)
#pragma unroll
            for (int nt = 0; nt < 2; ++nt)
                acc[mr][nt] = __builtin_amdgcn_mfma_f32_16x16x32_bf16(af[mr], bf[nt], acc[mr][nt], 0, 0, 0);
    }

#pragma unroll
    for (int nt = 0; nt < 2; ++nt) {
        int gn = n0 + wn * 32 + nt * 16 + lr;
        if (gn >= HID) continue;
        float bval = bias[gn];
#pragma unroll
        for (int mr = 0; mr < 4; ++mr)
#pragma unroll
            for (int r = 0; r < 4; ++r) {
                int m = m0 + wm * 64 + mr * 16 + lg * 4 + r;
                Cout[(size_t)m * HID + gn] = acc[mr][nt][r] + bval;
            }
    }
}

// ---------------------------------------------------------------------------
// LDS chunk swizzle (16B units) — same involution on stage (global src) and
// read (logical chunk) sides.
// ---------------------------------------------------------------------------
template<int DP>
__device__ __forceinline__ int kswz(int j, int rho) {
    if constexpr (DP == 32)      return j ^ (rho & 3);
    else if constexpr (DP == 64) return j ^ (rho & 7);
    else                         return (j & ~3) | ((j & 3) ^ (rho & 3));
}

// ---------------------------------------------------------------------------
// MFMA flash attention: cooperative 8-wave blocks, double-buffered LDS
// staging (global_load_lds), hoisted addressing, online softmax with DPP
// reductions, defer-rescale, raw v_exp_f32.
// ---------------------------------------------------------------------------
template<int DP>
__device__ __forceinline__
void attn_body(const ushort* __restrict__ qp, const ushort* __restrict__ kp,
               const ushort* __restrict__ vp, ushort* __restrict__ ctx,
               ushort* __restrict__ lds, int h, int b, int q0blk, int tid)
{
    constexpr int NDT  = DP / 16;
    constexpr int NXC  = DP / 32;
    constexpr int TILE = 64 * DP;

    int wave = tid >> 6, lane = tid & 63;
    int lr = lane & 15, lg = lane >> 4;
    int q0 = q0blk + wave * 16;

    int s0 = c_bounds[h];
    int d  = c_bounds[h + 1] - s0;

    size_t base = (size_t)b * PBE + ((size_t)c_cum[h] << 10);
    const ushort* Qb  = qp + base;
    const ushort* Kb  = kp + base;
    const ushort* Vtb = vp + base;

    ushort* Ps = lds + 4 * TILE + wave * 1024;
    int swz = (lr & 7) << 3;

    // ---------- hoisted staging pointers ----------
    const ushort *gK1, *gV1, *gK2, *gV2;
    ushort *lK1a, *lK1b, *lV1a, *lV1b, *lK2a, *lK2b, *lV2a, *lV2b;
    {
        if constexpr (DP == 32) {
            int rk = tid >> 2, ck = tid & 3;
            gK1 = Kb + (size_t)rk * DP + ((ck ^ (rk & 3)) * 8);
            int tv = tid & 255;
            int rv = tv >> 3, cv = tv & 7;
            gV1 = Vtb + ((size_t)rv << 10) + ((cv ^ (rv & 7)) * 8);
            lK1a = lds + tid * 8;            lK1b = lK1a + TILE;
            lV1a = lds + 2 * TILE + tv * 8;  lV1b = lV1a + TILE;
            gK2 = nullptr; gV2 = nullptr;
            lK2a = lK2b = lV2a = lV2b = nullptr;
        } else if constexpr (DP == 64) {
            int r = tid >> 3, c = tid & 7;
            gK1 = Kb + (size_t)r * DP + ((c ^ (r & 7)) * 8);
            gV1 = Vtb + ((size_t)r << 10) + ((c ^ (r & 7)) * 8);
            lK1a = lds + tid * 8;            lK1b = lK1a + TILE;
            lV1a = lds + 2 * TILE + tid * 8; lV1b = lV1a + TILE;
            gK2 = nullptr; gV2 = nullptr;
            lK2a = lK2b = lV2a = lV2b = nullptr;
        } else {
            int r1 = tid / 12, c1 = tid - r1 * 12;
            int cs1 = (c1 & ~3) | ((c1 & 3) ^ (r1 & 3));
            gK1 = Kb + (size_t)r1 * DP + cs1 * 8;
            int L = 512 + tid;
            int r2 = L / 12, c2 = L - r2 * 12;
            int cs2 = (c2 & ~3) | ((c2 & 3) ^ (r2 & 3));
            gK2 = Kb + (size_t)r2 * DP + cs2 * 8;
            int rv1 = tid >> 3, cv = tid & 7;
            gV1 = Vtb + ((size_t)rv1 << 10) + ((cv ^ (rv1 & 7)) * 8);
            int rv2 = 64 + (tid >> 3);
            gV2 = Vtb + ((size_t)rv2 << 10) + ((cv ^ (rv2 & 7)) * 8);
            lK1a = lds + tid * 8;                  lK1b = lK1a + TILE;
            lK2a = lds + (512 + tid) * 8;          lK2b = lK2a + TILE;
            lV1a = lds + 2 * TILE + tid * 8;       lV1b = lV1a + TILE;
            lV2a = lds + 2 * TILE + (512 + tid) * 8; lV2b = lV2a + TILE;
        }
    }

    auto do_stage = [&](ushort* dK1, ushort* dK2, ushort* dV1, ushort* dV2) {
        if constexpr (DP == 32) {
            if (tid < 256) { gld_lds16(gK1, dK1); gK1 += 64 * DP; }
            else           { gld_lds16(gV1, dV1); gV1 += 64; }
        } else if constexpr (DP == 64) {
            gld_lds16(gK1, dK1); gK1 += 64 * DP;
            gld_lds16(gV1, dV1); gV1 += 64;
        } else {
            gld_lds16(gK1, dK1); gK1 += 64 * DP;
            gld_lds16(gV1, dV1); gV1 += 64;
            if (tid < 256) {
                gld_lds16(gK2, dK2); gK2 += 64 * DP;
                gld_lds16(gV2, dV2); gV2 += 64;
            }
        }
    };

    // ---------- hoisted compute-side addresses ----------
    const ushort* krd[4][NXC];
#pragma unroll
    for (int ct = 0; ct < 4; ++ct) {
        int rho = ct * 16 + lr;
#pragma unroll
        for (int xc = 0; xc < NXC; ++xc) {
            int jj = lg + 4 * xc;
            krd[ct][xc] = lds + rho * DP + kswz<DP>(jj, rho) * 8;
        }
    }
    const ushort* vrd[NDT][2];
#pragma unroll
    for (int dt = 0; dt < NDT; ++dt) {
        int rv = dt * 16 + lr;
#pragma unroll
        for (int ks = 0; ks < 2; ++ks) {
            int jj = lg + 4 * ks;
            vrd[dt][ks] = lds + 2 * TILE + rv * 64 + ((jj ^ (rv & 7)) * 8);
        }
    }
    ushort* pw[4][4];
#pragma unroll
    for (int r = 0; r < 4; ++r) {
        int row = lg * 4 + r;
        int wsz = (row & 7) << 3;
#pragma unroll
        for (int ct = 0; ct < 4; ++ct)
            pw[r][ct] = Ps + row * 64 + ((lr + ct * 16) ^ wsz);
    }
    const ushort* prd0 = Ps + lr * 64 + ((lg * 8) ^ swz);
    const ushort* prd1 = Ps + lr * 64 + ((32 + lg * 8) ^ swz);

    bf16x8 aq[NXC];
    {
        int qrow = q0 + lr;
        const ushort* qr = Qb + (size_t)qrow * DP + lg * 8;
#pragma unroll
        for (int xc = 0; xc < NXC; ++xc)
            aq[xc] = *(const bf16x8*)(qr + xc * 32);
    }

    f32x4 o[NDT];
#pragma unroll
    for (int i = 0; i < NDT; ++i) o[i] = (f32x4){0.f, 0.f, 0.f, 0.f};
    float mrow[4] = {-1e30f, -1e30f, -1e30f, -1e30f};
    float lrow[4] = {0.f, 0.f, 0.f, 0.f};

    auto tile_compute = [&](int OFF) {
        f32x4 sc[4];
        __builtin_amdgcn_s_setprio(1);
#pragma unroll
        for (int ct = 0; ct < 4; ++ct) {
            f32x4 s = {0.f, 0.f, 0.f, 0.f};
#pragma unroll
            for (int xc = 0; xc < NXC; ++xc) {
                bf16x8 bk = *(const bf16x8*)(krd[ct][xc] + OFF);
                s = __builtin_amdgcn_mfma_f32_16x16x32_bf16(aq[xc], bk, s, 0, 0, 0);
            }
            sc[ct] = s;
        }
        __builtin_amdgcn_s_setprio(0);

        float mx[4];
#pragma unroll
        for (int r = 0; r < 4; ++r) {
            float m = fmaxf(fmaxf(sc[0][r], sc[1][r]), fmaxf(sc[2][r], sc[3][r]));
            m = dpp_max<0xB1>(m);
            m = dpp_max<0x4E>(m);
            m = dpp_max<0x141>(m);
            m = dpp_max<0x140>(m);
            mx[r] = m;
        }

        int grow = (mx[0] > mrow[0]) | (mx[1] > mrow[1])
                 | (mx[2] > mrow[2]) | (mx[3] > mrow[3]);
        if (__any(grow)) {
#pragma unroll
            for (int r = 0; r < 4; ++r) {
                float mnew = fmaxf(mrow[r], mx[r]);
                float fr = fexp2(mrow[r] - mnew);
                mrow[r] = mnew;
                lrow[r] *= fr;
#pragma unroll
                for (int dt = 0; dt < NDT; ++dt) o[dt][r] *= fr;
            }
        }

#pragma unroll
        for (int r = 0; r < 4; ++r) {
            float sum = 0.f;
#pragma unroll
            for (int ct = 0; ct < 4; ++ct) {
                float p = fexp2(sc[ct][r] - mrow[r]);
                sum += p;
                *pw[r][ct] = (ushort)((__builtin_bit_cast(unsigned, p) + 0x8000u) >> 16);
            }
            sum = dpp_add<0xB1>(sum);
            sum = dpp_add<0x4E>(sum);
            sum = dpp_add<0x141>(sum);
            sum = dpp_add<0x140>(sum);
            lrow[r] += sum;
        }

        bf16x8 ap0 = *(const bf16x8*)prd0;
        bf16x8 ap1 = *(const bf16x8*)prd1;

        __builtin_amdgcn_s_setprio(1);
#pragma unroll
        for (int dt = 0; dt < NDT; ++dt) {
            bf16x8 bv0 = *(const bf16x8*)(vrd[dt][0] + OFF);
            bf16x8 bv1 = *(const bf16x8*)(vrd[dt][1] + OFF);
            o[dt] = __builtin_amdgcn_mfma_f32_16x16x32_bf16(ap0, bv0, o[dt], 0, 0, 0);
            o[dt] = __builtin_amdgcn_mfma_f32_16x16x32_bf16(ap1, bv1, o[dt], 0, 0, 0);
        }
        __builtin_amdgcn_s_setprio(0);
    };

    do_stage(lK1a, lK2a, lV1a, lV2a);
    for (int t = 0; t < SEQ / 64; t += 2) {
        __syncthreads();
        if (t + 1 < SEQ / 64) do_stage(lK1b, lK2b, lV1b, lV2b);
        tile_compute(0);
        __syncthreads();
        if (t + 2 < SEQ / 64) do_stage(lK1a, lK2a, lV1a, lV2a);
        tile_compute(TILE);
    }

#pragma unroll
    for (int r = 0; r < 4; ++r) {
        float inv = 1.0f / lrow[r];
        int q = q0 + lg * 4 + r;
        ushort* dst = ctx + ((size_t)(b << 10) + q) * KP + s0;
#pragma unroll
        for (int dt = 0; dt < NDT; ++dt) {
            int dv = lr + 16 * dt;
            if (dv < d) dst[dv] = f2bf(o[dt][r] * inv);
        }
    }
}

__global__ __launch_bounds__(512, 4)
void attn_mfma(const ushort* __restrict__ qp, const ushort* __restrict__ kp,
               const ushort* __restrict__ vp, ushort* __restrict__ ctx)
{
    __shared__ ushort lds[32768];            // 64 KB: K dbuf | V dbuf | 8x Ps
    int tid = threadIdx.x;
    // Longest-job-first + XCD-group dispatch (bijective).
    int i = blockIdx.x;
    int xcd = i & 7, j = i >> 3;
    int qblk = j & 7;
    int rank = xcd + 8 * (j >> 3);           // 0..143
    int b, h;
    if (rank < 32)      { b = rank >> 1;      h = 7 + (rank & 1); }   // DP96
    else if (rank < 96) { int rr = rank - 32; b = rr >> 2; h = 3 + (rr & 3); } // DP64
    else                { int rr = rank - 96; b = rr / 3;  h = rr % 3; }       // DP32
    int q0 = qblk * 128;
    if (h < 3)      attn_body<32>(qp, kp, vp, ctx, lds, h, b, q0, tid);
    else if (h < 7) attn_body<64>(qp, kp, vp, ctx, lds, h, b, q0, tid);
    else            attn_body<96>(qp, kp, vp, ctx, lds, h, b, q0, tid);
}

// ---------------------------------------------------------------------------
extern "C" void kernel_launch(void* const* d_in, const int* in_sizes, int n_in,
                              void* d_out, int out_size, void* d_ws, size_t ws_size,
                              hipStream_t stream)
{
    const float* hs = (const float*)d_in[0];
    const float* Wq = (const float*)d_in[1];
    const float* bq = (const float*)d_in[2];
    const float* Wk = (const float*)d_in[3];
    const float* bk = (const float*)d_in[4];
    const float* Wv = (const float*)d_in[5];
    const float* bv = (const float*)d_in[6];
    const float* Wo = (const float*)d_in[7];
    const float* bo = (const float*)d_in[8];

    size_t pelem = (size_t)BATCH * PBE;            // 8,912,896 per tensor
    ushort* qp  = (ushort*)d_ws;
    ushort* kp  = qp + pelem;
    ushort* vp  = kp + pelem;
    ushort* ctx = vp + pelem;                      // bf16 [16384][448]
    ushort* wt  = ctx + (size_t)BATCH * SEQ * KP;  // 4 x [448][448] bf16
    ushort* hsb = (ushort*)d_out;                  // bf16 hs, dead before final GEMM writes

    // zero q/k/v pads + ctx pad cols (contiguous region)
    hipMemsetAsync(d_ws, 0, (3 * pelem + (size_t)BATCH * SEQ * KP) * sizeof(ushort), stream);

    convert_hs<<<BATCH * SEQ * 56 / 256, 256, 0, stream>>>(hs, hsb);
    convert_w<<<dim3(KP * 56 / 256, 4), 256, 0, stream>>>(Wq, Wk, Wv, Wo, wt);

    dim3 gq(BATCH * SEQ / 128, KP / 64);           // fused QKV: 128 x 7
    gemm_qkv<<<gq, 256, 0, stream>>>(hsb, wt, bq, bk, bv, qp, kp, vp);

    attn_mfma<<<8 * 144, 512, 0, stream>>>(qp, kp, vp, ctx);

    dim3 gg(BATCH * SEQ / 128, KP / 64);           // 128 x 7
    gemm_out<<<gg, 256, 0, stream>>>(ctx, wt + 3 * (size_t)WTS, bo, (float*)d_out);
}

// Round 22
// 181.954 us; speedup vs baseline: 1.0286x; 1.0286x over previous
//
#include <hip/hip_runtime.h>
#include <math.h>

#define BATCH 16
#define SEQ   1024
#define HID   441
#define NH    9
#define KP    448                 // padded hidden (K and N dim of GEMMs)
#define PB    544                 // sum of padded head dims
#define PBE   (SEQ * PB)          // padded elems per batch
#define WTS   (KP * KP)           // one transposed weight matrix

typedef __attribute__((ext_vector_type(8))) short bf16x8;
typedef __attribute__((ext_vector_type(4))) float f32x4;

__constant__ int c_bounds[NH + 1] = {0, 7, 21, 49, 105, 161, 217, 273, 357, 441};
__constant__ int c_dpad[NH] = {32, 32, 32, 64, 64, 64, 64, 96, 96};
__constant__ int c_cum[NH]  = {0, 32, 64, 96, 160, 224, 288, 352, 448};

__device__ __forceinline__ ushort f2bf(float x) {
    union { float f; unsigned u; } v; v.f = x;
    unsigned r = v.u + 0x7FFF + ((v.u >> 16) & 1);   // RNE
    return (ushort)(r >> 16);
}

__device__ __forceinline__ void gld_lds16(const ushort* g, ushort* l) {
    __builtin_amdgcn_global_load_lds(
        (const __attribute__((address_space(1))) unsigned int*)g,
        (__attribute__((address_space(3))) unsigned int*)l, 16, 0, 0);
}

// raw hardware exp2: single v_exp_f32 (args always <= 0 here)
__device__ __forceinline__ float fexp2(float x) {
    return __builtin_amdgcn_exp2f(x);
}

// DPP 16-lane reduction steps (pure VALU — no ds_bpermute):
template<int CTRL>
__device__ __forceinline__ float dpp_max(float x) {
    int m = __builtin_amdgcn_update_dpp(0, __builtin_bit_cast(int, x), CTRL, 0xF, 0xF, true);
    return fmaxf(x, __builtin_bit_cast(float, m));
}
template<int CTRL>
__device__ __forceinline__ float dpp_add(float x) {
    int m = __builtin_amdgcn_update_dpp(0, __builtin_bit_cast(int, x), CTRL, 0xF, 0xF, true);
    return x + __builtin_bit_cast(float, m);
}

// ---------------------------------------------------------------------------
// hs fp32 [16384][441] -> bf16 [16384][448] (pad cols zeroed)
// ---------------------------------------------------------------------------
__global__ __launch_bounds__(256)
void convert_hs(const float* __restrict__ hs, ushort* __restrict__ out)
{
    int t = blockIdx.x * 256 + threadIdx.x;   // 16384*56 threads
    int r = t / 56, cc = t % 56;
    const float* src = hs + (size_t)r * HID + cc * 8;
    union { ushort u[8]; bf16x8 v; } pk;
#pragma unroll
    for (int j = 0; j < 8; ++j) {
        int c = cc * 8 + j;
        pk.u[j] = (c < HID) ? f2bf(src[j]) : (ushort)0;
    }
    *(bf16x8*)(out + (size_t)r * KP + cc * 8) = pk.v;
}

// ---------------------------------------------------------------------------
// W fp32 [441][441] -> W^T bf16 [448][448] (pads zero). blockIdx.y = matrix.
// ---------------------------------------------------------------------------
__global__ __launch_bounds__(256)
void convert_w(const float* __restrict__ W0, const float* __restrict__ W1,
               const float* __restrict__ W2, const float* __restrict__ W3,
               ushort* __restrict__ wt)
{
    const float* W = (blockIdx.y == 0) ? W0 : (blockIdx.y == 1) ? W1
                   : (blockIdx.y == 2) ? W2 : W3;
    ushort* out = wt + (size_t)blockIdx.y * WTS;
    int t = blockIdx.x * 256 + threadIdx.x;   // 448*56 threads
    int n = t / 56, kc = t % 56;
    union { ushort u[8]; bf16x8 v; } pk;
#pragma unroll
    for (int j = 0; j < 8; ++j) {
        int k = kc * 8 + j;
        pk.u[j] = (k < HID && n < HID) ? f2bf(W[(size_t)k * HID + n]) : (ushort)0;
    }
    *(bf16x8*)(out + (size_t)n * KP + kc * 8) = pk.v;
}

// ---------------------------------------------------------------------------
// FULLY-FUSED QKV bf16 MFMA GEMM, 128x64 tile, BK=32, 4 waves (2x2).
// A-tile staged once per K-step; af[] reused across z; 3 accumulator sets.
// z=0: Q -> padded [b][h][s][dp], PRE-SCALED by log2e/sqrt(d)
// z=1: K -> padded [b][h][s][dp]
// z=2: V -> transposed [b][h][dv][s]
// ---------------------------------------------------------------------------
__global__ __launch_bounds__(256)
void gemm_qkv(const ushort* __restrict__ A, const ushort* __restrict__ wt,
              const float* __restrict__ bq, const float* __restrict__ bk,
              const float* __restrict__ bv, ushort* __restrict__ qp,
              ushort* __restrict__ kp, ushort* __restrict__ vp)
{
    __shared__ ushort As[2][128 * 32];       // 16 KB
    __shared__ ushort Bs[2][3][64 * 32];     // 24 KB

    int tid = threadIdx.x;
    int wid = tid >> 6, lane = tid & 63;
    int wm = wid >> 1, wn = wid & 1;
    int lr = lane & 15, lg = lane >> 4;
    int m0 = blockIdx.x * 128, n0 = blockIdx.y * 64;

    const ushort* a_src = A + (size_t)(m0 + (tid >> 2)) * KP + (tid & 3) * 8;
    const ushort* b_src = wt + (size_t)(n0 + (tid >> 2)) * KP + (tid & 3) * 8;

    f32x4 acc[3][4][2];
#pragma unroll
    for (int z = 0; z < 3; ++z)
#pragma unroll
        for (int i = 0; i < 4; ++i)
#pragma unroll
            for (int j = 0; j < 2; ++j) acc[z][i][j] = (f32x4){0.f, 0.f, 0.f, 0.f};

    auto stage = [&](int buf, int k0) {
        gld_lds16(a_src + k0,                     &As[buf][tid * 8]);
        gld_lds16(a_src + 64 * KP + k0,           &As[buf][2048 + tid * 8]);
        gld_lds16(b_src + k0,                     &Bs[buf][0][tid * 8]);
        gld_lds16(b_src + (size_t)WTS + k0,       &Bs[buf][1][tid * 8]);
        gld_lds16(b_src + 2 * (size_t)WTS + k0,   &Bs[buf][2][tid * 8]);
    };

    stage(0, 0);
#pragma unroll 2
    for (int t = 0; t < 14; ++t) {
        int buf = t & 1;
        __syncthreads();                       // buf staged, prev reads done
        if (t < 13) stage(buf ^ 1, (t + 1) * 32);

        bf16x8 af[4];
#pragma unroll
        for (int mr = 0; mr < 4; ++mr)
            af[mr] = *(const bf16x8*)&As[buf][(wm * 64 + mr * 16 + lr) * 32 + lg * 8];

#pragma unroll
        for (int z = 0; z < 3; ++z) {
            bf16x8 bf[2];
#pragma unroll
            for (int nt = 0; nt < 2; ++nt)
                bf[nt] = *(const bf16x8*)&Bs[buf][z][(wn * 32 + nt * 16 + lr) * 32 + lg * 8];
#pragma unroll
            for (int mr = 0; mr < 4; ++mr)
#pragma unroll
                for (int nt = 0; nt < 2; ++nt)
                    acc[z][mr][nt] = __builtin_amdgcn_mfma_f32_16x16x32_bf16(af[mr], bf[nt], acc[z][mr][nt], 0, 0, 0);
        }
    }

    // ---- epilogue (verbatim per-z paths) ----
    int bb = m0 >> 10;
    int srow = (m0 & 1023) + wm * 64;

#pragma unroll
    for (int z = 0; z < 3; ++z) {
        const float* bias = (z == 0) ? bq : (z == 1) ? bk : bv;
#pragma unroll
        for (int nt = 0; nt < 2; ++nt) {
            int gn = n0 + wn * 32 + nt * 16 + lr;
            bool ok = gn < HID;
            int gcl = ok ? gn : 0;
            float bval = ok ? bias[gcl] : 0.f;
            int hh = 0;
            while (gcl >= c_bounds[hh + 1]) ++hh;
            int off = gcl - c_bounds[hh];
            int dph = c_dpad[hh];
            size_t hbase = (size_t)bb * PBE + ((size_t)c_cum[hh] << 10);
            float cs = (z == 0)
                     ? rsqrtf((float)(c_bounds[hh + 1] - c_bounds[hh])) * 1.44269504f
                     : 1.0f;

#pragma unroll
            for (int mr = 0; mr < 4; ++mr)
#pragma unroll
                for (int r = 0; r < 4; ++r) {
                    if (!ok) continue;
                    int s = srow + mr * 16 + lg * 4 + r;
                    float val = (acc[z][mr][nt][r] + bval) * cs;
                    if (z == 0) {
                        qp[hbase + (size_t)s * dph + off] = f2bf(val);
                    } else if (z == 1) {
                        kp[hbase + (size_t)s * dph + off] = f2bf(val);
                    } else {
                        vp[hbase + ((size_t)off << 10) + s] = f2bf(val);
                    }
                }
        }
    }
}

// ---------------------------------------------------------------------------
// O-projection bf16 MFMA GEMM, 128x64 tile: out[16384][441] fp32 = ctx@Wo^T+bo
// ---------------------------------------------------------------------------
__global__ __launch_bounds__(256)
void gemm_out(const ushort* __restrict__ A, const ushort* __restrict__ Bt,
              const float* __restrict__ bias, float* __restrict__ Cout)
{
    __shared__ ushort As[2][128 * 32];
    __shared__ ushort Bs[2][64 * 32];

    int tid = threadIdx.x;
    int wid = tid >> 6, lane = tid & 63;
    int wm = wid >> 1, wn = wid & 1;
    int lr = lane & 15, lg = lane >> 4;
    int m0 = blockIdx.x * 128, n0 = blockIdx.y * 64;

    const ushort* a_src = A + (size_t)(m0 + (tid >> 2)) * KP + (tid & 3) * 8;
    const ushort* b_src = Bt + (size_t)(n0 + (tid >> 2)) * KP + (tid & 3) * 8;

    f32x4 acc[4][2];
#pragma unroll
    for (int i = 0; i < 4; ++i)
#pragma unroll
        for (int j = 0; j < 2; ++j) acc[i][j] = (f32x4){0.f, 0.f, 0.f, 0.f};

    auto stage = [&](int buf, int k0) {
        gld_lds16(a_src + k0,            &As[buf][tid * 8]);
        gld_lds16(a_src + 64 * KP + k0,  &As[buf][2048 + tid * 8]);
        gld_lds16(b_src + k0,            &Bs[buf][tid * 8]);
    };

    stage(0, 0);
#pragma unroll 2
    for (int t = 0; t < 14; ++t) {
        int buf = t & 1;
        __syncthreads();
        if (t < 13) stage(buf ^ 1, (t + 1) * 32);

        bf16x8 af[4], bf[2];
#pragma unroll
        for (int mr = 0; mr < 4; ++mr)
            af[mr] = *(const bf16x8*)&As[buf][(wm * 64 + mr * 16 + lr) * 32 + lg * 8];
#pragma unroll
        for (int nt = 0; nt < 2; ++nt)
            bf[nt] = *(const bf16x8*)&Bs[buf][(wn * 32 + nt * 16 + lr) * 32 + lg * 8];
#pragma unroll
        for (int mr = 0; mr < 4; ++mr)
#pragma unroll
            for (int nt = 0; nt < 2; ++nt)
                acc[mr][nt] = __builtin_amdgcn_mfma_f32_16x16x32_bf16(af[mr], bf[nt], acc[mr][nt], 0, 0, 0);
    }

#pragma unroll
    for (int nt = 0; nt < 2; ++nt) {
        int gn = n0 + wn * 32 + nt * 16 + lr;
        if (gn >= HID) continue;
        float bval = bias[gn];
#pragma unroll
        for (int mr = 0; mr < 4; ++mr)
#pragma unroll
            for (int r = 0; r < 4; ++r) {
                int m = m0 + wm * 64 + mr * 16 + lg * 4 + r;
                Cout[(size_t)m * HID + gn] = acc[mr][nt][r] + bval;
            }
    }
}

// ---------------------------------------------------------------------------
// LDS chunk swizzle (16B units) — same involution on stage (global src) and
// read (logical chunk) sides.
// ---------------------------------------------------------------------------
template<int DP>
__device__ __forceinline__ int kswz(int j, int rho) {
    if constexpr (DP == 32)      return j ^ (rho & 3);
    else if constexpr (DP == 64) return j ^ (rho & 7);
    else                         return (j & ~3) | ((j & 3) ^ (rho & 3));
}

// ---------------------------------------------------------------------------
// MFMA flash attention: cooperative 8-wave blocks, double-buffered LDS
// staging, hoisted addressing, online softmax with DPP max reduction,
// defer-rescale, raw v_exp_f32, and DEFERRED SUM: lrow is a per-lane
// partial (sum butterfly moved from per-tile to the epilogue — linearity
// + row-uniform rescale make this exact up to one reassociation).
// ---------------------------------------------------------------------------
template<int DP>
__device__ __forceinline__
void attn_body(const ushort* __restrict__ qp, const ushort* __restrict__ kp,
               const ushort* __restrict__ vp, ushort* __restrict__ ctx,
               ushort* __restrict__ lds, int h, int b, int q0blk, int tid)
{
    constexpr int NDT  = DP / 16;
    constexpr int NXC  = DP / 32;
    constexpr int TILE = 64 * DP;

    int wave = tid >> 6, lane = tid & 63;
    int lr = lane & 15, lg = lane >> 4;
    int q0 = q0blk + wave * 16;

    int s0 = c_bounds[h];
    int d  = c_bounds[h + 1] - s0;

    size_t base = (size_t)b * PBE + ((size_t)c_cum[h] << 10);
    const ushort* Qb  = qp + base;
    const ushort* Kb  = kp + base;
    const ushort* Vtb = vp + base;

    ushort* Ps = lds + 4 * TILE + wave * 1024;
    int swz = (lr & 7) << 3;

    // ---------- hoisted staging pointers ----------
    const ushort *gK1, *gV1, *gK2, *gV2;
    ushort *lK1a, *lK1b, *lV1a, *lV1b, *lK2a, *lK2b, *lV2a, *lV2b;
    {
        if constexpr (DP == 32) {
            int rk = tid >> 2, ck = tid & 3;
            gK1 = Kb + (size_t)rk * DP + ((ck ^ (rk & 3)) * 8);
            int tv = tid & 255;
            int rv = tv >> 3, cv = tv & 7;
            gV1 = Vtb + ((size_t)rv << 10) + ((cv ^ (rv & 7)) * 8);
            lK1a = lds + tid * 8;            lK1b = lK1a + TILE;
            lV1a = lds + 2 * TILE + tv * 8;  lV1b = lV1a + TILE;
            gK2 = nullptr; gV2 = nullptr;
            lK2a = lK2b = lV2a = lV2b = nullptr;
        } else if constexpr (DP == 64) {
            int r = tid >> 3, c = tid & 7;
            gK1 = Kb + (size_t)r * DP + ((c ^ (r & 7)) * 8);
            gV1 = Vtb + ((size_t)r << 10) + ((c ^ (r & 7)) * 8);
            lK1a = lds + tid * 8;            lK1b = lK1a + TILE;
            lV1a = lds + 2 * TILE + tid * 8; lV1b = lV1a + TILE;
            gK2 = nullptr; gV2 = nullptr;
            lK2a = lK2b = lV2a = lV2b = nullptr;
        } else {
            int r1 = tid / 12, c1 = tid - r1 * 12;
            int cs1 = (c1 & ~3) | ((c1 & 3) ^ (r1 & 3));
            gK1 = Kb + (size_t)r1 * DP + cs1 * 8;
            int L = 512 + tid;
            int r2 = L / 12, c2 = L - r2 * 12;
            int cs2 = (c2 & ~3) | ((c2 & 3) ^ (r2 & 3));
            gK2 = Kb + (size_t)r2 * DP + cs2 * 8;
            int rv1 = tid >> 3, cv = tid & 7;
            gV1 = Vtb + ((size_t)rv1 << 10) + ((cv ^ (rv1 & 7)) * 8);
            int rv2 = 64 + (tid >> 3);
            gV2 = Vtb + ((size_t)rv2 << 10) + ((cv ^ (rv2 & 7)) * 8);
            lK1a = lds + tid * 8;                  lK1b = lK1a + TILE;
            lK2a = lds + (512 + tid) * 8;          lK2b = lK2a + TILE;
            lV1a = lds + 2 * TILE + tid * 8;       lV1b = lV1a + TILE;
            lV2a = lds + 2 * TILE + (512 + tid) * 8; lV2b = lV2a + TILE;
        }
    }

    auto do_stage = [&](ushort* dK1, ushort* dK2, ushort* dV1, ushort* dV2) {
        if constexpr (DP == 32) {
            if (tid < 256) { gld_lds16(gK1, dK1); gK1 += 64 * DP; }
            else           { gld_lds16(gV1, dV1); gV1 += 64; }
        } else if constexpr (DP == 64) {
            gld_lds16(gK1, dK1); gK1 += 64 * DP;
            gld_lds16(gV1, dV1); gV1 += 64;
        } else {
            gld_lds16(gK1, dK1); gK1 += 64 * DP;
            gld_lds16(gV1, dV1); gV1 += 64;
            if (tid < 256) {
                gld_lds16(gK2, dK2); gK2 += 64 * DP;
                gld_lds16(gV2, dV2); gV2 += 64;
            }
        }
    };

    // ---------- hoisted compute-side addresses ----------
    const ushort* krd[4][NXC];
#pragma unroll
    for (int ct = 0; ct < 4; ++ct) {
        int rho = ct * 16 + lr;
#pragma unroll
        for (int xc = 0; xc < NXC; ++xc) {
            int jj = lg + 4 * xc;
            krd[ct][xc] = lds + rho * DP + kswz<DP>(jj, rho) * 8;
        }
    }
    const ushort* vrd[NDT][2];
#pragma unroll
    for (int dt = 0; dt < NDT; ++dt) {
        int rv = dt * 16 + lr;
#pragma unroll
        for (int ks = 0; ks < 2; ++ks) {
            int jj = lg + 4 * ks;
            vrd[dt][ks] = lds + 2 * TILE + rv * 64 + ((jj ^ (rv & 7)) * 8);
        }
    }
    ushort* pw[4][4];
#pragma unroll
    for (int r = 0; r < 4; ++r) {
        int row = lg * 4 + r;
        int wsz = (row & 7) << 3;
#pragma unroll
        for (int ct = 0; ct < 4; ++ct)
            pw[r][ct] = Ps + row * 64 + ((lr + ct * 16) ^ wsz);
    }
    const ushort* prd0 = Ps + lr * 64 + ((lg * 8) ^ swz);
    const ushort* prd1 = Ps + lr * 64 + ((32 + lg * 8) ^ swz);

    bf16x8 aq[NXC];
    {
        int qrow = q0 + lr;
        const ushort* qr = Qb + (size_t)qrow * DP + lg * 8;
#pragma unroll
        for (int xc = 0; xc < NXC; ++xc)
            aq[xc] = *(const bf16x8*)(qr + xc * 32);
    }

    f32x4 o[NDT];
#pragma unroll
    for (int i = 0; i < NDT; ++i) o[i] = (f32x4){0.f, 0.f, 0.f, 0.f};
    float mrow[4] = {-1e30f, -1e30f, -1e30f, -1e30f};
    float lrow[4] = {0.f, 0.f, 0.f, 0.f};   // PER-LANE partial sums

    auto tile_compute = [&](int OFF) {
        f32x4 sc[4];
        __builtin_amdgcn_s_setprio(1);
#pragma unroll
        for (int ct = 0; ct < 4; ++ct) {
            f32x4 s = {0.f, 0.f, 0.f, 0.f};
#pragma unroll
            for (int xc = 0; xc < NXC; ++xc) {
                bf16x8 bk = *(const bf16x8*)(krd[ct][xc] + OFF);
                s = __builtin_amdgcn_mfma_f32_16x16x32_bf16(aq[xc], bk, s, 0, 0, 0);
            }
            sc[ct] = s;
        }
        __builtin_amdgcn_s_setprio(0);

        float mx[4];
#pragma unroll
        for (int r = 0; r < 4; ++r) {
            float m = fmaxf(fmaxf(sc[0][r], sc[1][r]), fmaxf(sc[2][r], sc[3][r]));
            m = dpp_max<0xB1>(m);
            m = dpp_max<0x4E>(m);
            m = dpp_max<0x141>(m);
            m = dpp_max<0x140>(m);
            mx[r] = m;
        }

        int grow = (mx[0] > mrow[0]) | (mx[1] > mrow[1])
                 | (mx[2] > mrow[2]) | (mx[3] > mrow[3]);
        if (__any(grow)) {
#pragma unroll
            for (int r = 0; r < 4; ++r) {
                float mnew = fmaxf(mrow[r], mx[r]);
                float fr = fexp2(mrow[r] - mnew);
                mrow[r] = mnew;
                lrow[r] *= fr;                   // per-lane partial rescale
#pragma unroll
                for (int dt = 0; dt < NDT; ++dt) o[dt][r] *= fr;
            }
        }

#pragma unroll
        for (int r = 0; r < 4; ++r) {
            float sum = 0.f;
#pragma unroll
            for (int ct = 0; ct < 4; ++ct) {
                float p = fexp2(sc[ct][r] - mrow[r]);
                sum += p;
                *pw[r][ct] = (ushort)((__builtin_bit_cast(unsigned, p) + 0x8000u) >> 16);
            }
            lrow[r] += sum;                      // NO butterfly here (deferred)
        }

        bf16x8 ap0 = *(const bf16x8*)prd0;
        bf16x8 ap1 = *(const bf16x8*)prd1;

        __builtin_amdgcn_s_setprio(1);
#pragma unroll
        for (int dt = 0; dt < NDT; ++dt) {
            bf16x8 bv0 = *(const bf16x8*)(vrd[dt][0] + OFF);
            bf16x8 bv1 = *(const bf16x8*)(vrd[dt][1] + OFF);
            o[dt] = __builtin_amdgcn_mfma_f32_16x16x32_bf16(ap0, bv0, o[dt], 0, 0, 0);
            o[dt] = __builtin_amdgcn_mfma_f32_16x16x32_bf16(ap1, bv1, o[dt], 0, 0, 0);
        }
        __builtin_amdgcn_s_setprio(0);
    };

    do_stage(lK1a, lK2a, lV1a, lV2a);
    for (int t = 0; t < SEQ / 64; t += 2) {
        __syncthreads();
        if (t + 1 < SEQ / 64) do_stage(lK1b, lK2b, lV1b, lV2b);
        tile_compute(0);
        __syncthreads();
        if (t + 2 < SEQ / 64) do_stage(lK1a, lK2a, lV1a, lV2a);
        tile_compute(TILE);
    }

    // ---- deferred 16-lane sum butterfly (once per row), then write ctx ----
#pragma unroll
    for (int r = 0; r < 4; ++r) {
        float s = lrow[r];
        s = dpp_add<0xB1>(s);
        s = dpp_add<0x4E>(s);
        s = dpp_add<0x141>(s);
        s = dpp_add<0x140>(s);
        float inv = 1.0f / s;
        int q = q0 + lg * 4 + r;
        ushort* dst = ctx + ((size_t)(b << 10) + q) * KP + s0;
#pragma unroll
        for (int dt = 0; dt < NDT; ++dt) {
            int dv = lr + 16 * dt;
            if (dv < d) dst[dv] = f2bf(o[dt][r] * inv);
        }
    }
}

__global__ __launch_bounds__(512, 4)
void attn_mfma(const ushort* __restrict__ qp, const ushort* __restrict__ kp,
               const ushort* __restrict__ vp, ushort* __restrict__ ctx)
{
    __shared__ ushort lds[32768];            // 64 KB: K dbuf | V dbuf | 8x Ps
    int tid = threadIdx.x;
    // Longest-job-first + XCD-group dispatch (bijective).
    int i = blockIdx.x;
    int xcd = i & 7, j = i >> 3;
    int qblk = j & 7;
    int rank = xcd + 8 * (j >> 3);           // 0..143
    int b, h;
    if (rank < 32)      { b = rank >> 1;      h = 7 + (rank & 1); }   // DP96
    else if (rank < 96) { int rr = rank - 32; b = rr >> 2; h = 3 + (rr & 3); } // DP64
    else                { int rr = rank - 96; b = rr / 3;  h = rr % 3; }       // DP32
    int q0 = qblk * 128;
    if (h < 3)      attn_body<32>(qp, kp, vp, ctx, lds, h, b, q0, tid);
    else if (h < 7) attn_body<64>(qp, kp, vp, ctx, lds, h, b, q0, tid);
    else            attn_body<96>(qp, kp, vp, ctx, lds, h, b, q0, tid);
}

// ---------------------------------------------------------------------------
extern "C" void kernel_launch(void* const* d_in, const int* in_sizes, int n_in,
                              void* d_out, int out_size, void* d_ws, size_t ws_size,
                              hipStream_t stream)
{
    const float* hs = (const float*)d_in[0];
    const float* Wq = (const float*)d_in[1];
    const float* bq = (const float*)d_in[2];
    const float* Wk = (const float*)d_in[3];
    const float* bk = (const float*)d_in[4];
    const float* Wv = (const float*)d_in[5];
    const float* bv = (const float*)d_in[6];
    const float* Wo = (const float*)d_in[7];
    const float* bo = (const float*)d_in[8];

    size_t pelem = (size_t)BATCH * PBE;            // 8,912,896 per tensor
    ushort* qp  = (ushort*)d_ws;
    ushort* kp  = qp + pelem;
    ushort* vp  = kp + pelem;
    ushort* ctx = vp + pelem;                      // bf16 [16384][448]
    ushort* wt  = ctx + (size_t)BATCH * SEQ * KP;  // 4 x [448][448] bf16
    ushort* hsb = (ushort*)d_out;                  // bf16 hs, dead before final GEMM writes

    // zero q/k/v pads + ctx pad cols (contiguous region)
    hipMemsetAsync(d_ws, 0, (3 * pelem + (size_t)BATCH * SEQ * KP) * sizeof(ushort), stream);

    convert_hs<<<BATCH * SEQ * 56 / 256, 256, 0, stream>>>(hs, hsb);
    convert_w<<<dim3(KP * 56 / 256, 4), 256, 0, stream>>>(Wq, Wk, Wv, Wo, wt);

    dim3 gq(BATCH * SEQ / 128, KP / 64);           // fused QKV: 128 x 7
    gemm_qkv<<<gq, 256, 0, stream>>>(hsb, wt, bq, bk, bv, qp, kp, vp);

    attn_mfma<<<8 * 144, 512, 0, stream>>>(qp, kp, vp, ctx);

    dim3 gg(BATCH * SEQ / 128, KP / 64);           // 128 x 7
    gemm_out<<<gg, 256, 0, stream>>>(ctx, wt + 3 * (size_t)WTS, bo, (float*)d_out);
}

// Round 23
// 179.263 us; speedup vs baseline: 1.0441x; 1.0150x over previous
//
#include <hip/hip_runtime.h>
#include <math.h>

#define BATCH 16
#define SEQ   1024
#define HID   441
#define NH    9
#define KP    448                 // padded hidden (K and N dim of GEMMs)
#define PB    544                 // sum of padded head dims
#define PBE   (SEQ * PB)          // padded elems per batch
#define WTS   (KP * KP)           // one transposed weight matrix

typedef __attribute__((ext_vector_type(8))) short bf16x8;
typedef __attribute__((ext_vector_type(4))) float f32x4;

__constant__ int c_bounds[NH + 1] = {0, 7, 21, 49, 105, 161, 217, 273, 357, 441};
__constant__ int c_dpad[NH] = {32, 32, 32, 64, 64, 64, 64, 96, 96};
__constant__ int c_cum[NH]  = {0, 32, 64, 96, 160, 224, 288, 352, 448};

__device__ __forceinline__ ushort f2bf(float x) {
    union { float f; unsigned u; } v; v.f = x;
    unsigned r = v.u + 0x7FFF + ((v.u >> 16) & 1);   // RNE
    return (ushort)(r >> 16);
}

__device__ __forceinline__ void gld_lds16(const ushort* g, ushort* l) {
    __builtin_amdgcn_global_load_lds(
        (const __attribute__((address_space(1))) unsigned int*)g,
        (__attribute__((address_space(3))) unsigned int*)l, 16, 0, 0);
}

// raw hardware exp2: single v_exp_f32 (args always <= 0 here)
__device__ __forceinline__ float fexp2(float x) {
    return __builtin_amdgcn_exp2f(x);
}

// DPP 16-lane reduction steps (pure VALU — no ds_bpermute):
template<int CTRL>
__device__ __forceinline__ float dpp_max(float x) {
    int m = __builtin_amdgcn_update_dpp(0, __builtin_bit_cast(int, x), CTRL, 0xF, 0xF, true);
    return fmaxf(x, __builtin_bit_cast(float, m));
}
template<int CTRL>
__device__ __forceinline__ float dpp_add(float x) {
    int m = __builtin_amdgcn_update_dpp(0, __builtin_bit_cast(int, x), CTRL, 0xF, 0xF, true);
    return x + __builtin_bit_cast(float, m);
}

// ---------------------------------------------------------------------------
// hs fp32 [16384][441] -> bf16 [16384][448] (pad cols zeroed)
// ---------------------------------------------------------------------------
__global__ __launch_bounds__(256)
void convert_hs(const float* __restrict__ hs, ushort* __restrict__ out)
{
    int t = blockIdx.x * 256 + threadIdx.x;   // 16384*56 threads
    int r = t / 56, cc = t % 56;
    const float* src = hs + (size_t)r * HID + cc * 8;
    union { ushort u[8]; bf16x8 v; } pk;
#pragma unroll
    for (int j = 0; j < 8; ++j) {
        int c = cc * 8 + j;
        pk.u[j] = (c < HID) ? f2bf(src[j]) : (ushort)0;
    }
    *(bf16x8*)(out + (size_t)r * KP + cc * 8) = pk.v;
}

// ---------------------------------------------------------------------------
// W fp32 [441][441] -> W^T bf16 [448][448] (pads zero). blockIdx.y = matrix.
// ---------------------------------------------------------------------------
__global__ __launch_bounds__(256)
void convert_w(const float* __restrict__ W0, const float* __restrict__ W1,
               const float* __restrict__ W2, const float* __restrict__ W3,
               ushort* __restrict__ wt)
{
    const float* W = (blockIdx.y == 0) ? W0 : (blockIdx.y == 1) ? W1
                   : (blockIdx.y == 2) ? W2 : W3;
    ushort* out = wt + (size_t)blockIdx.y * WTS;
    int t = blockIdx.x * 256 + threadIdx.x;   // 448*56 threads
    int n = t / 56, kc = t % 56;
    union { ushort u[8]; bf16x8 v; } pk;
#pragma unroll
    for (int j = 0; j < 8; ++j) {
        int k = kc * 8 + j;
        pk.u[j] = (k < HID && n < HID) ? f2bf(W[(size_t)k * HID + n]) : (ushort)0;
    }
    *(bf16x8*)(out + (size_t)n * KP + kc * 8) = pk.v;
}

// ---------------------------------------------------------------------------
// FULLY-FUSED QKV bf16 MFMA GEMM, 128x64 tile, BK=32, 4 waves (2x2).
// A-tile staged once per K-step; af[] reused across z; 3 accumulator sets.
// z=0: Q -> padded [b][h][s][dp], PRE-SCALED by log2e/sqrt(d)
// z=1: K -> padded [b][h][s][dp]
// z=2: V -> transposed [b][h][dv][s]
// ---------------------------------------------------------------------------
__global__ __launch_bounds__(256)
void gemm_qkv(const ushort* __restrict__ A, const ushort* __restrict__ wt,
              const float* __restrict__ bq, const float* __restrict__ bk,
              const float* __restrict__ bv, ushort* __restrict__ qp,
              ushort* __restrict__ kp, ushort* __restrict__ vp)
{
    __shared__ ushort As[2][128 * 32];       // 16 KB
    __shared__ ushort Bs[2][3][64 * 32];     // 24 KB

    int tid = threadIdx.x;
    int wid = tid >> 6, lane = tid & 63;
    int wm = wid >> 1, wn = wid & 1;
    int lr = lane & 15, lg = lane >> 4;
    int m0 = blockIdx.x * 128, n0 = blockIdx.y * 64;

    const ushort* a_src = A + (size_t)(m0 + (tid >> 2)) * KP + (tid & 3) * 8;
    const ushort* b_src = wt + (size_t)(n0 + (tid >> 2)) * KP + (tid & 3) * 8;

    f32x4 acc[3][4][2];
#pragma unroll
    for (int z = 0; z < 3; ++z)
#pragma unroll
        for (int i = 0; i < 4; ++i)
#pragma unroll
            for (int j = 0; j < 2; ++j) acc[z][i][j] = (f32x4){0.f, 0.f, 0.f, 0.f};

    auto stage = [&](int buf, int k0) {
        gld_lds16(a_src + k0,                     &As[buf][tid * 8]);
        gld_lds16(a_src + 64 * KP + k0,           &As[buf][2048 + tid * 8]);
        gld_lds16(b_src + k0,                     &Bs[buf][0][tid * 8]);
        gld_lds16(b_src + (size_t)WTS + k0,       &Bs[buf][1][tid * 8]);
        gld_lds16(b_src + 2 * (size_t)WTS + k0,   &Bs[buf][2][tid * 8]);
    };

    stage(0, 0);
#pragma unroll 2
    for (int t = 0; t < 14; ++t) {
        int buf = t & 1;
        __syncthreads();                       // buf staged, prev reads done
        if (t < 13) stage(buf ^ 1, (t + 1) * 32);

        bf16x8 af[4];
#pragma unroll
        for (int mr = 0; mr < 4; ++mr)
            af[mr] = *(const bf16x8*)&As[buf][(wm * 64 + mr * 16 + lr) * 32 + lg * 8];

#pragma unroll
        for (int z = 0; z < 3; ++z) {
            bf16x8 bf[2];
#pragma unroll
            for (int nt = 0; nt < 2; ++nt)
                bf[nt] = *(const bf16x8*)&Bs[buf][z][(wn * 32 + nt * 16 + lr) * 32 + lg * 8];
#pragma unroll
            for (int mr = 0; mr < 4; ++mr)
#pragma unroll
                for (int nt = 0; nt < 2; ++nt)
                    acc[z][mr][nt] = __builtin_amdgcn_mfma_f32_16x16x32_bf16(af[mr], bf[nt], acc[z][mr][nt], 0, 0, 0);
        }
    }

    // ---- epilogue (verbatim per-z paths) ----
    int bb = m0 >> 10;
    int srow = (m0 & 1023) + wm * 64;

#pragma unroll
    for (int z = 0; z < 3; ++z) {
        const float* bias = (z == 0) ? bq : (z == 1) ? bk : bv;
#pragma unroll
        for (int nt = 0; nt < 2; ++nt) {
            int gn = n0 + wn * 32 + nt * 16 + lr;
            bool ok = gn < HID;
            int gcl = ok ? gn : 0;
            float bval = ok ? bias[gcl] : 0.f;
            int hh = 0;
            while (gcl >= c_bounds[hh + 1]) ++hh;
            int off = gcl - c_bounds[hh];
            int dph = c_dpad[hh];
            size_t hbase = (size_t)bb * PBE + ((size_t)c_cum[hh] << 10);
            float cs = (z == 0)
                     ? rsqrtf((float)(c_bounds[hh + 1] - c_bounds[hh])) * 1.44269504f
                     : 1.0f;

#pragma unroll
            for (int mr = 0; mr < 4; ++mr)
#pragma unroll
                for (int r = 0; r < 4; ++r) {
                    if (!ok) continue;
                    int s = srow + mr * 16 + lg * 4 + r;
                    float val = (acc[z][mr][nt][r] + bval) * cs;
                    if (z == 0) {
                        qp[hbase + (size_t)s * dph + off] = f2bf(val);
                    } else if (z == 1) {
                        kp[hbase + (size_t)s * dph + off] = f2bf(val);
                    } else {
                        vp[hbase + ((size_t)off << 10) + s] = f2bf(val);
                    }
                }
        }
    }
}

// ---------------------------------------------------------------------------
// O-projection bf16 MFMA GEMM, 128x64 tile: out[16384][441] fp32 = ctx@Wo^T+bo
// ---------------------------------------------------------------------------
__global__ __launch_bounds__(256)
void gemm_out(const ushort* __restrict__ A, const ushort* __restrict__ Bt,
              const float* __restrict__ bias, float* __restrict__ Cout)
{
    __shared__ ushort As[2][128 * 32];
    __shared__ ushort Bs[2][64 * 32];

    int tid = threadIdx.x;
    int wid = tid >> 6, lane = tid & 63;
    int wm = wid >> 1, wn = wid & 1;
    int lr = lane & 15, lg = lane >> 4;
    int m0 = blockIdx.x * 128, n0 = blockIdx.y * 64;

    const ushort* a_src = A + (size_t)(m0 + (tid >> 2)) * KP + (tid & 3) * 8;
    const ushort* b_src = Bt + (size_t)(n0 + (tid >> 2)) * KP + (tid & 3) * 8;

    f32x4 acc[4][2];
#pragma unroll
    for (int i = 0; i < 4; ++i)
#pragma unroll
        for (int j = 0; j < 2; ++j) acc[i][j] = (f32x4){0.f, 0.f, 0.f, 0.f};

    auto stage = [&](int buf, int k0) {
        gld_lds16(a_src + k0,            &As[buf][tid * 8]);
        gld_lds16(a_src + 64 * KP + k0,  &As[buf][2048 + tid * 8]);
        gld_lds16(b_src + k0,            &Bs[buf][tid * 8]);
    };

    stage(0, 0);
#pragma unroll 2
    for (int t = 0; t < 14; ++t) {
        int buf = t & 1;
        __syncthreads();
        if (t < 13) stage(buf ^ 1, (t + 1) * 32);

        bf16x8 af[4], bf[2];
#pragma unroll
        for (int mr = 0; mr < 4; ++mr)
            af[mr] = *(const bf16x8*)&As[buf][(wm * 64 + mr * 16 + lr) * 32 + lg * 8];
#pragma unroll
        for (int nt = 0; nt < 2; ++nt)
            bf[nt] = *(const bf16x8*)&Bs[buf][(wn * 32 + nt * 16 + lr) * 32 + lg * 8];
#pragma unroll
        for (int mr = 0; mr < 4; ++mr)
#pragma unroll
            for (int nt = 0; nt < 2; ++nt)
                acc[mr][nt] = __builtin_amdgcn_mfma_f32_16x16x32_bf16(af[mr], bf[nt], acc[mr][nt], 0, 0, 0);
    }

#pragma unroll
    for (int nt = 0; nt < 2; ++nt) {
        int gn = n0 + wn * 32 + nt * 16 + lr;
        if (gn >= HID) continue;
        float bval = bias[gn];
#pragma unroll
        for (int mr = 0; mr < 4; ++mr)
#pragma unroll
            for (int r = 0; r < 4; ++r) {
                int m = m0 + wm * 64 + mr * 16 + lg * 4 + r;
                Cout[(size_t)m * HID + gn] = acc[mr][nt][r] + bval;
            }
    }
}

// ---------------------------------------------------------------------------
// LDS chunk swizzle (16B units) — same involution on stage (global src) and
// read (logical chunk) sides.
// ---------------------------------------------------------------------------
template<int DP>
__device__ __forceinline__ int kswz(int j, int rho) {
    if constexpr (DP == 32)      return j ^ (rho & 3);
    else if constexpr (DP == 64) return j ^ (rho & 7);
    else                         return (j & ~3) | ((j & 3) ^ (rho & 3));
}

// ---------------------------------------------------------------------------
// MFMA flash attention: cooperative 8-wave blocks, double-buffered LDS
// staging, hoisted addressing, raw v_exp_f32, deferred sum butterfly, and
// now DEFERRED MAX BUTTERFLY: the 16-lane DPP max reduction runs only when
// some lane's in-lane max exceeds mrow (exact — skipped tiles have fr==1
// and mnew==mrow bitwise).
// ---------------------------------------------------------------------------
template<int DP>
__device__ __forceinline__
void attn_body(const ushort* __restrict__ qp, const ushort* __restrict__ kp,
               const ushort* __restrict__ vp, ushort* __restrict__ ctx,
               ushort* __restrict__ lds, int h, int b, int q0blk, int tid)
{
    constexpr int NDT  = DP / 16;
    constexpr int NXC  = DP / 32;
    constexpr int TILE = 64 * DP;

    int wave = tid >> 6, lane = tid & 63;
    int lr = lane & 15, lg = lane >> 4;
    int q0 = q0blk + wave * 16;

    int s0 = c_bounds[h];
    int d  = c_bounds[h + 1] - s0;

    size_t base = (size_t)b * PBE + ((size_t)c_cum[h] << 10);
    const ushort* Qb  = qp + base;
    const ushort* Kb  = kp + base;
    const ushort* Vtb = vp + base;

    ushort* Ps = lds + 4 * TILE + wave * 1024;
    int swz = (lr & 7) << 3;

    // ---------- hoisted staging pointers ----------
    const ushort *gK1, *gV1, *gK2, *gV2;
    ushort *lK1a, *lK1b, *lV1a, *lV1b, *lK2a, *lK2b, *lV2a, *lV2b;
    {
        if constexpr (DP == 32) {
            int rk = tid >> 2, ck = tid & 3;
            gK1 = Kb + (size_t)rk * DP + ((ck ^ (rk & 3)) * 8);
            int tv = tid & 255;
            int rv = tv >> 3, cv = tv & 7;
            gV1 = Vtb + ((size_t)rv << 10) + ((cv ^ (rv & 7)) * 8);
            lK1a = lds + tid * 8;            lK1b = lK1a + TILE;
            lV1a = lds + 2 * TILE + tv * 8;  lV1b = lV1a + TILE;
            gK2 = nullptr; gV2 = nullptr;
            lK2a = lK2b = lV2a = lV2b = nullptr;
        } else if constexpr (DP == 64) {
            int r = tid >> 3, c = tid & 7;
            gK1 = Kb + (size_t)r * DP + ((c ^ (r & 7)) * 8);
            gV1 = Vtb + ((size_t)r << 10) + ((c ^ (r & 7)) * 8);
            lK1a = lds + tid * 8;            lK1b = lK1a + TILE;
            lV1a = lds + 2 * TILE + tid * 8; lV1b = lV1a + TILE;
            gK2 = nullptr; gV2 = nullptr;
            lK2a = lK2b = lV2a = lV2b = nullptr;
        } else {
            int r1 = tid / 12, c1 = tid - r1 * 12;
            int cs1 = (c1 & ~3) | ((c1 & 3) ^ (r1 & 3));
            gK1 = Kb + (size_t)r1 * DP + cs1 * 8;
            int L = 512 + tid;
            int r2 = L / 12, c2 = L - r2 * 12;
            int cs2 = (c2 & ~3) | ((c2 & 3) ^ (r2 & 3));
            gK2 = Kb + (size_t)r2 * DP + cs2 * 8;
            int rv1 = tid >> 3, cv = tid & 7;
            gV1 = Vtb + ((size_t)rv1 << 10) + ((cv ^ (rv1 & 7)) * 8);
            int rv2 = 64 + (tid >> 3);
            gV2 = Vtb + ((size_t)rv2 << 10) + ((cv ^ (rv2 & 7)) * 8);
            lK1a = lds + tid * 8;                  lK1b = lK1a + TILE;
            lK2a = lds + (512 + tid) * 8;          lK2b = lK2a + TILE;
            lV1a = lds + 2 * TILE + tid * 8;       lV1b = lV1a + TILE;
            lV2a = lds + 2 * TILE + (512 + tid) * 8; lV2b = lV2a + TILE;
        }
    }

    auto do_stage = [&](ushort* dK1, ushort* dK2, ushort* dV1, ushort* dV2) {
        if constexpr (DP == 32) {
            if (tid < 256) { gld_lds16(gK1, dK1); gK1 += 64 * DP; }
            else           { gld_lds16(gV1, dV1); gV1 += 64; }
        } else if constexpr (DP == 64) {
            gld_lds16(gK1, dK1); gK1 += 64 * DP;
            gld_lds16(gV1, dV1); gV1 += 64;
        } else {
            gld_lds16(gK1, dK1); gK1 += 64 * DP;
            gld_lds16(gV1, dV1); gV1 += 64;
            if (tid < 256) {
                gld_lds16(gK2, dK2); gK2 += 64 * DP;
                gld_lds16(gV2, dV2); gV2 += 64;
            }
        }
    };

    // ---------- hoisted compute-side addresses ----------
    const ushort* krd[4][NXC];
#pragma unroll
    for (int ct = 0; ct < 4; ++ct) {
        int rho = ct * 16 + lr;
#pragma unroll
        for (int xc = 0; xc < NXC; ++xc) {
            int jj = lg + 4 * xc;
            krd[ct][xc] = lds + rho * DP + kswz<DP>(jj, rho) * 8;
        }
    }
    const ushort* vrd[NDT][2];
#pragma unroll
    for (int dt = 0; dt < NDT; ++dt) {
        int rv = dt * 16 + lr;
#pragma unroll
        for (int ks = 0; ks < 2; ++ks) {
            int jj = lg + 4 * ks;
            vrd[dt][ks] = lds + 2 * TILE + rv * 64 + ((jj ^ (rv & 7)) * 8);
        }
    }
    ushort* pw[4][4];
#pragma unroll
    for (int r = 0; r < 4; ++r) {
        int row = lg * 4 + r;
        int wsz = (row & 7) << 3;
#pragma unroll
        for (int ct = 0; ct < 4; ++ct)
            pw[r][ct] = Ps + row * 64 + ((lr + ct * 16) ^ wsz);
    }
    const ushort* prd0 = Ps + lr * 64 + ((lg * 8) ^ swz);
    const ushort* prd1 = Ps + lr * 64 + ((32 + lg * 8) ^ swz);

    bf16x8 aq[NXC];
    {
        int qrow = q0 + lr;
        const ushort* qr = Qb + (size_t)qrow * DP + lg * 8;
#pragma unroll
        for (int xc = 0; xc < NXC; ++xc)
            aq[xc] = *(const bf16x8*)(qr + xc * 32);
    }

    f32x4 o[NDT];
#pragma unroll
    for (int i = 0; i < NDT; ++i) o[i] = (f32x4){0.f, 0.f, 0.f, 0.f};
    float mrow[4] = {-1e30f, -1e30f, -1e30f, -1e30f};
    float lrow[4] = {0.f, 0.f, 0.f, 0.f};   // PER-LANE partial sums

    auto tile_compute = [&](int OFF) {
        f32x4 sc[4];
        __builtin_amdgcn_s_setprio(1);
#pragma unroll
        for (int ct = 0; ct < 4; ++ct) {
            f32x4 s = {0.f, 0.f, 0.f, 0.f};
#pragma unroll
            for (int xc = 0; xc < NXC; ++xc) {
                bf16x8 bk = *(const bf16x8*)(krd[ct][xc] + OFF);
                s = __builtin_amdgcn_mfma_f32_16x16x32_bf16(aq[xc], bk, s, 0, 0, 0);
            }
            sc[ct] = s;
        }
        __builtin_amdgcn_s_setprio(0);

        // ---- in-lane max only (3 fmax); full butterfly deferred ----
        float plm[4];
#pragma unroll
        for (int r = 0; r < 4; ++r)
            plm[r] = fmaxf(fmaxf(sc[0][r], sc[1][r]), fmaxf(sc[2][r], sc[3][r]));

        // grow iff some lane's local max exceeds mrow (=> row max may grow).
        // If no lane grows, row max <= mrow => butterfly+rescale is identity.
        int grow = (plm[0] > mrow[0]) | (plm[1] > mrow[1])
                 | (plm[2] > mrow[2]) | (plm[3] > mrow[3]);
        if (__any(grow)) {
#pragma unroll
            for (int r = 0; r < 4; ++r) {
                float m = plm[r];
                m = dpp_max<0xB1>(m);
                m = dpp_max<0x4E>(m);
                m = dpp_max<0x141>(m);
                m = dpp_max<0x140>(m);
                float mnew = fmaxf(mrow[r], m);
                float fr = fexp2(mrow[r] - mnew);
                mrow[r] = mnew;
                lrow[r] *= fr;                   // per-lane partial rescale
#pragma unroll
                for (int dt = 0; dt < NDT; ++dt) o[dt][r] *= fr;
            }
        }

#pragma unroll
        for (int r = 0; r < 4; ++r) {
            float sum = 0.f;
#pragma unroll
            for (int ct = 0; ct < 4; ++ct) {
                float p = fexp2(sc[ct][r] - mrow[r]);
                sum += p;
                *pw[r][ct] = (ushort)((__builtin_bit_cast(unsigned, p) + 0x8000u) >> 16);
            }
            lrow[r] += sum;                      // butterfly deferred to epilogue
        }

        bf16x8 ap0 = *(const bf16x8*)prd0;
        bf16x8 ap1 = *(const bf16x8*)prd1;

        __builtin_amdgcn_s_setprio(1);
#pragma unroll
        for (int dt = 0; dt < NDT; ++dt) {
            bf16x8 bv0 = *(const bf16x8*)(vrd[dt][0] + OFF);
            bf16x8 bv1 = *(const bf16x8*)(vrd[dt][1] + OFF);
            o[dt] = __builtin_amdgcn_mfma_f32_16x16x32_bf16(ap0, bv0, o[dt], 0, 0, 0);
            o[dt] = __builtin_amdgcn_mfma_f32_16x16x32_bf16(ap1, bv1, o[dt], 0, 0, 0);
        }
        __builtin_amdgcn_s_setprio(0);
    };

    do_stage(lK1a, lK2a, lV1a, lV2a);
    for (int t = 0; t < SEQ / 64; t += 2) {
        __syncthreads();
        if (t + 1 < SEQ / 64) do_stage(lK1b, lK2b, lV1b, lV2b);
        tile_compute(0);
        __syncthreads();
        if (t + 2 < SEQ / 64) do_stage(lK1a, lK2a, lV1a, lV2a);
        tile_compute(TILE);
    }

    // ---- deferred 16-lane sum butterfly (once per row), then write ctx ----
#pragma unroll
    for (int r = 0; r < 4; ++r) {
        float s = lrow[r];
        s = dpp_add<0xB1>(s);
        s = dpp_add<0x4E>(s);
        s = dpp_add<0x141>(s);
        s = dpp_add<0x140>(s);
        float inv = 1.0f / s;
        int q = q0 + lg * 4 + r;
        ushort* dst = ctx + ((size_t)(b << 10) + q) * KP + s0;
#pragma unroll
        for (int dt = 0; dt < NDT; ++dt) {
            int dv = lr + 16 * dt;
            if (dv < d) dst[dv] = f2bf(o[dt][r] * inv);
        }
    }
}

__global__ __launch_bounds__(512, 4)
void attn_mfma(const ushort* __restrict__ qp, const ushort* __restrict__ kp,
               const ushort* __restrict__ vp, ushort* __restrict__ ctx)
{
    __shared__ ushort lds[32768];            // 64 KB: K dbuf | V dbuf | 8x Ps
    int tid = threadIdx.x;
    // Longest-job-first + XCD-group dispatch (bijective).
    int i = blockIdx.x;
    int xcd = i & 7, j = i >> 3;
    int qblk = j & 7;
    int rank = xcd + 8 * (j >> 3);           // 0..143
    int b, h;
    if (rank < 32)      { b = rank >> 1;      h = 7 + (rank & 1); }   // DP96
    else if (rank < 96) { int rr = rank - 32; b = rr >> 2; h = 3 + (rr & 3); } // DP64
    else                { int rr = rank - 96; b = rr / 3;  h = rr % 3; }       // DP32
    int q0 = qblk * 128;
    if (h < 3)      attn_body<32>(qp, kp, vp, ctx, lds, h, b, q0, tid);
    else if (h < 7) attn_body<64>(qp, kp, vp, ctx, lds, h, b, q0, tid);
    else            attn_body<96>(qp, kp, vp, ctx, lds, h, b, q0, tid);
}

// ---------------------------------------------------------------------------
extern "C" void kernel_launch(void* const* d_in, const int* in_sizes, int n_in,
                              void* d_out, int out_size, void* d_ws, size_t ws_size,
                              hipStream_t stream)
{
    const float* hs = (const float*)d_in[0];
    const float* Wq = (const float*)d_in[1];
    const float* bq = (const float*)d_in[2];
    const float* Wk = (const float*)d_in[3];
    const float* bk = (const float*)d_in[4];
    const float* Wv = (const float*)d_in[5];
    const float* bv = (const float*)d_in[6];
    const float* Wo = (const float*)d_in[7];
    const float* bo = (const float*)d_in[8];

    size_t pelem = (size_t)BATCH * PBE;            // 8,912,896 per tensor
    ushort* qp  = (ushort*)d_ws;
    ushort* kp  = qp + pelem;
    ushort* vp  = kp + pelem;
    ushort* ctx = vp + pelem;                      // bf16 [16384][448]
    ushort* wt  = ctx + (size_t)BATCH * SEQ * KP;  // 4 x [448][448] bf16
    ushort* hsb = (ushort*)d_out;                  // bf16 hs, dead before final GEMM writes

    // zero q/k/v pads + ctx pad cols (contiguous region)
    hipMemsetAsync(d_ws, 0, (3 * pelem + (size_t)BATCH * SEQ * KP) * sizeof(ushort), stream);

    convert_hs<<<BATCH * SEQ * 56 / 256, 256, 0, stream>>>(hs, hsb);
    convert_w<<<dim3(KP * 56 / 256, 4), 256, 0, stream>>>(Wq, Wk, Wv, Wo, wt);

    dim3 gq(BATCH * SEQ / 128, KP / 64);           // fused QKV: 128 x 7
    gemm_qkv<<<gq, 256, 0, stream>>>(hsb, wt, bq, bk, bv, qp, kp, vp);

    attn_mfma<<<8 * 144, 512, 0, stream>>>(qp, kp, vp, ctx);

    dim3 gg(BATCH * SEQ / 128, KP / 64);           // 128 x 7
    gemm_out<<<gg, 256, 0, stream>>>(ctx, wt + 3 * (size_t)WTS, bo, (float*)d_out);
}